// Round 4
// baseline (861.580 us; speedup 1.0000x reference)
//
#include <hip/hip_runtime.h>
#include <hip/hip_bf16.h>
#include <stdint.h>
#include <stddef.h>

// MoBA forward, MI355X.
//  split hs -> bf16 hi/lo; transpose-cast W's -> B^T bf16
//  GEMM1 (bf16 MFMA, reg-prefetch pipeline): qkv[2048][6144] bf16
//  fp32 gate path: hsmean -> kg (fp32) -> wg = Wq_h @ kg_h (fp32)
//    gate partials = bf16x3 MFMA split 6 ways (3 phases x 2 K-halves) for occupancy
//  gate_topk: sums 6 partials, rank-based top-8 -> 32-bit block mask per (h,s)
//  attn: block-sparse flash, 1 workgroup (4 waves) per (h, 64-row q-block)
//  GEMM2 (64x64 tile, 1024 blocks): o @ Wo -> d_out fp32

using bh = __bf16;
typedef __bf16 bhx8 __attribute__((ext_vector_type(8)));
typedef __bf16 bhx4 __attribute__((ext_vector_type(4)));
typedef float  f32x4 __attribute__((ext_vector_type(4)));

#define SEQ   2048
#define HIDN  2048
#define NHEAD 16
#define HDIM  128
#define NBLK  32
#define BLKSZ 64
#define NQKV  6144
#define NGATE 512   // NBLK*NHEAD gate columns
#define LDK   72    // padded LDS row stride for GEMM tiles (64+8)
#define LDKK  136   // attn K-tile row stride (128+8)
#define LDVV  72    // attn V-tile row stride (64+8)
#define PSTRIDE ((size_t)SEQ * NGATE)   // gate partial plane stride

// ---------------- split fp32 -> bf16 hi + lo ----------------
__global__ __launch_bounds__(256) void split_f32(const float* __restrict__ in,
                                                 bh* __restrict__ hi, bh* __restrict__ lo, int n) {
  int i = (blockIdx.x * 256 + threadIdx.x) * 4;
  if (i >= n) return;
  float4 v = *(const float4*)(in + i);
  bhx4 h4, l4;
  float vv[4] = {v.x, v.y, v.z, v.w};
#pragma unroll
  for (int e = 0; e < 4; e++) {
    bh h = (bh)vv[e];
    h4[e] = h;
    l4[e] = (bh)(vv[e] - (float)h);
  }
  *(bhx4*)(hi + i) = h4;
  *(bhx4*)(lo + i) = l4;
}

// ---------------- transpose + cast: in[R][C] fp32 -> out[C][R] bf16 ----------------
__global__ __launch_bounds__(256) void transpose_cast(const float* __restrict__ in,
                                                      bh* __restrict__ out, int R, int C) {
  __shared__ float tile[32][33];
  int tx = threadIdx.x, ty = threadIdx.y;
  int c0 = blockIdx.x * 32, r0 = blockIdx.y * 32;
#pragma unroll
  for (int i = 0; i < 4; i++)
    tile[ty + i * 8][tx] = in[(size_t)(r0 + ty + i * 8) * C + c0 + tx];
  __syncthreads();
#pragma unroll
  for (int i = 0; i < 4; i++)
    out[(size_t)(c0 + ty + i * 8) * R + r0 + tx] = (bh)tile[tx][ty + i * 8];
}

// ---------------- bf16 MFMA GEMM 128x128, B^T layout, reg-prefetch pipeline ----------------
// C[M][N] = A[M][K] * BT[N][K]^T ; writes bf16 Cb
__global__ __launch_bounds__(256) void gemm_bt(const bh* __restrict__ A, const bh* __restrict__ BT,
                                               bh* __restrict__ Cb, int M, int N, int K) {
  __shared__ __align__(16) bh As[128 * LDK];
  __shared__ __align__(16) bh Bs[128 * LDK];
  const int t = threadIdx.x;
  const int L = t & 63, w = t >> 6;
  const int wm = w & 1, wn = w >> 1;
  const int quad = L >> 4, lo = L & 15;
  const int m0 = blockIdx.y * 128, n0 = blockIdx.x * 128;

  f32x4 acc[4][4];
#pragma unroll
  for (int i = 0; i < 4; i++)
#pragma unroll
    for (int j = 0; j < 4; j++) acc[i][j] = (f32x4){0.f, 0.f, 0.f, 0.f};

  uint4 ra[4], rb[4];
#pragma unroll
  for (int c = 0; c < 4; c++) {
    int i = c * 256 + t;
    int row = i >> 3, cg = i & 7;
    ra[c] = *(const uint4*)(A + (size_t)(m0 + row) * K + cg * 8);
    rb[c] = *(const uint4*)(BT + (size_t)(n0 + row) * K + cg * 8);
  }

  for (int k0 = 0; k0 < K; k0 += 64) {
#pragma unroll
    for (int c = 0; c < 4; c++) {
      int i = c * 256 + t;
      int row = i >> 3, cg = i & 7;
      *(uint4*)&As[row * LDK + cg * 8] = ra[c];
      *(uint4*)&Bs[row * LDK + cg * 8] = rb[c];
    }
    __syncthreads();
    if (k0 + 64 < K) {
#pragma unroll
      for (int c = 0; c < 4; c++) {
        int i = c * 256 + t;
        int row = i >> 3, cg = i & 7;
        ra[c] = *(const uint4*)(A + (size_t)(m0 + row) * K + k0 + 64 + cg * 8);
        rb[c] = *(const uint4*)(BT + (size_t)(n0 + row) * K + k0 + 64 + cg * 8);
      }
    }
#pragma unroll
    for (int ks = 0; ks < 2; ks++) {
      bhx8 af[4], bf_[4];
#pragma unroll
      for (int i = 0; i < 4; i++)
        af[i] = *(const bhx8*)&As[(wm * 64 + i * 16 + lo) * LDK + ks * 32 + quad * 8];
#pragma unroll
      for (int j = 0; j < 4; j++)
        bf_[j] = *(const bhx8*)&Bs[(wn * 64 + j * 16 + lo) * LDK + ks * 32 + quad * 8];
#pragma unroll
      for (int i = 0; i < 4; i++)
#pragma unroll
        for (int j = 0; j < 4; j++)
          acc[i][j] = __builtin_amdgcn_mfma_f32_16x16x32_bf16(af[i], bf_[j], acc[i][j], 0, 0, 0);
    }
    __syncthreads();
  }

#pragma unroll
  for (int i = 0; i < 4; i++)
#pragma unroll
    for (int j = 0; j < 4; j++)
#pragma unroll
      for (int r = 0; r < 4; r++) {
        int row = m0 + wm * 64 + i * 16 + quad * 4 + r;
        int col = n0 + wn * 64 + j * 16 + lo;
        Cb[(size_t)row * N + col] = (bh)acc[i][j][r];
      }
}

// ---------------- bf16 MFMA GEMM 64x64, B^T layout, fp32 out (o-projection) ----------------
__global__ __launch_bounds__(256) void gemm_bt64(const bh* __restrict__ A, const bh* __restrict__ BT,
                                                 float* __restrict__ Cf, int M, int N, int K) {
  __shared__ __align__(16) bh As[64 * LDK];
  __shared__ __align__(16) bh Bs[64 * LDK];
  const int t = threadIdx.x;
  const int L = t & 63, w = t >> 6;
  const int wm = w & 1, wn = w >> 1;
  const int quad = L >> 4, lo = L & 15;
  const int m0 = blockIdx.y * 64, n0 = blockIdx.x * 64;

  f32x4 acc[2][2];
#pragma unroll
  for (int i = 0; i < 2; i++)
#pragma unroll
    for (int j = 0; j < 2; j++) acc[i][j] = (f32x4){0.f, 0.f, 0.f, 0.f};

  uint4 ra[2], rb[2];
#pragma unroll
  for (int c = 0; c < 2; c++) {
    int i = c * 256 + t;
    int row = i >> 3, cg = i & 7;
    ra[c] = *(const uint4*)(A + (size_t)(m0 + row) * K + cg * 8);
    rb[c] = *(const uint4*)(BT + (size_t)(n0 + row) * K + cg * 8);
  }

  for (int k0 = 0; k0 < K; k0 += 64) {
#pragma unroll
    for (int c = 0; c < 2; c++) {
      int i = c * 256 + t;
      int row = i >> 3, cg = i & 7;
      *(uint4*)&As[row * LDK + cg * 8] = ra[c];
      *(uint4*)&Bs[row * LDK + cg * 8] = rb[c];
    }
    __syncthreads();
    if (k0 + 64 < K) {
#pragma unroll
      for (int c = 0; c < 2; c++) {
        int i = c * 256 + t;
        int row = i >> 3, cg = i & 7;
        ra[c] = *(const uint4*)(A + (size_t)(m0 + row) * K + k0 + 64 + cg * 8);
        rb[c] = *(const uint4*)(BT + (size_t)(n0 + row) * K + k0 + 64 + cg * 8);
      }
    }
#pragma unroll
    for (int ks = 0; ks < 2; ks++) {
      bhx8 af[2], bf_[2];
#pragma unroll
      for (int i = 0; i < 2; i++)
        af[i] = *(const bhx8*)&As[(wm * 32 + i * 16 + lo) * LDK + ks * 32 + quad * 8];
#pragma unroll
      for (int j = 0; j < 2; j++)
        bf_[j] = *(const bhx8*)&Bs[(wn * 32 + j * 16 + lo) * LDK + ks * 32 + quad * 8];
#pragma unroll
      for (int i = 0; i < 2; i++)
#pragma unroll
        for (int j = 0; j < 2; j++)
          acc[i][j] = __builtin_amdgcn_mfma_f32_16x16x32_bf16(af[i], bf_[j], acc[i][j], 0, 0, 0);
    }
    __syncthreads();
  }

#pragma unroll
  for (int i = 0; i < 2; i++)
#pragma unroll
    for (int j = 0; j < 2; j++)
#pragma unroll
      for (int r = 0; r < 4; r++) {
        int row = m0 + wm * 32 + i * 16 + quad * 4 + r;
        int col = n0 + wn * 32 + j * 16 + lo;
        Cf[(size_t)row * N + col] = acc[i][j][r];
      }
}

// ---------------- gate GEMM, 6-way split for occupancy ----------------
// z = phase*2 + khalf; phase 0: hi@wgh, 1: lo@wgh, 2: hi@wgl; K=1024 each.
// part[z][2048][512] fp32. 64x64 tile, grid (8,32,6) = 1536 blocks.
__global__ __launch_bounds__(256) void gemm_gate_split(const bh* __restrict__ hs_hi,
                                                       const bh* __restrict__ hs_lo,
                                                       const bh* __restrict__ wg_hi,
                                                       const bh* __restrict__ wg_lo,
                                                       float* __restrict__ part) {
  __shared__ __align__(16) bh As[64 * LDK];
  __shared__ __align__(16) bh Bs[64 * LDK];
  const int t = threadIdx.x;
  const int L = t & 63, w = t >> 6;
  const int wm = w & 1, wn = w >> 1;
  const int quad = L >> 4, lo = L & 15;
  const int m0 = blockIdx.y * 64, n0 = blockIdx.x * 64;
  const int z = blockIdx.z;
  const bh* Ap = ((z >> 1) == 1) ? hs_lo : hs_hi;
  const bh* Bp = ((z >> 1) == 2) ? wg_lo : wg_hi;
  const int kb = (z & 1) * 1024;

  f32x4 acc[2][2];
#pragma unroll
  for (int i = 0; i < 2; i++)
#pragma unroll
    for (int j = 0; j < 2; j++) acc[i][j] = (f32x4){0.f, 0.f, 0.f, 0.f};

  uint4 ra[2], rb[2];
#pragma unroll
  for (int c = 0; c < 2; c++) {
    int i = c * 256 + t;
    int row = i >> 3, cg = i & 7;
    ra[c] = *(const uint4*)(Ap + (size_t)(m0 + row) * HIDN + kb + cg * 8);
    rb[c] = *(const uint4*)(Bp + (size_t)(n0 + row) * HIDN + kb + cg * 8);
  }

  for (int k0 = 0; k0 < 1024; k0 += 64) {
#pragma unroll
    for (int c = 0; c < 2; c++) {
      int i = c * 256 + t;
      int row = i >> 3, cg = i & 7;
      *(uint4*)&As[row * LDK + cg * 8] = ra[c];
      *(uint4*)&Bs[row * LDK + cg * 8] = rb[c];
    }
    __syncthreads();
    if (k0 + 64 < 1024) {
#pragma unroll
      for (int c = 0; c < 2; c++) {
        int i = c * 256 + t;
        int row = i >> 3, cg = i & 7;
        ra[c] = *(const uint4*)(Ap + (size_t)(m0 + row) * HIDN + kb + k0 + 64 + cg * 8);
        rb[c] = *(const uint4*)(Bp + (size_t)(n0 + row) * HIDN + kb + k0 + 64 + cg * 8);
      }
    }
#pragma unroll
    for (int ks = 0; ks < 2; ks++) {
      bhx8 af[2], bf_[2];
#pragma unroll
      for (int i = 0; i < 2; i++)
        af[i] = *(const bhx8*)&As[(wm * 32 + i * 16 + lo) * LDK + ks * 32 + quad * 8];
#pragma unroll
      for (int j = 0; j < 2; j++)
        bf_[j] = *(const bhx8*)&Bs[(wn * 32 + j * 16 + lo) * LDK + ks * 32 + quad * 8];
#pragma unroll
      for (int i = 0; i < 2; i++)
#pragma unroll
        for (int j = 0; j < 2; j++)
          acc[i][j] = __builtin_amdgcn_mfma_f32_16x16x32_bf16(af[i], bf_[j], acc[i][j], 0, 0, 0);
    }
    __syncthreads();
  }

#pragma unroll
  for (int i = 0; i < 2; i++)
#pragma unroll
    for (int j = 0; j < 2; j++)
#pragma unroll
      for (int r = 0; r < 4; r++) {
        int row = m0 + wm * 32 + i * 16 + quad * 4 + r;
        int col = n0 + wn * 32 + j * 16 + lo;
        part[(size_t)z * PSTRIDE + (size_t)row * NGATE + col] = acc[i][j][r];
      }
}

// ---------------- hsmean: block-mean of hs fp32 -> [NBLK][HIDN] ----------------
__global__ __launch_bounds__(256) void hsmean_k(const float* __restrict__ hs, float* __restrict__ hsm) {
  int idx = blockIdx.x * 256 + threadIdx.x;   // 65536
  int n = idx >> 11, c = idx & 2047;
  const float* p = hs + (size_t)(n * BLKSZ) * HIDN + c;
  float s = 0.f;
#pragma unroll 8
  for (int r = 0; r < BLKSZ; r++) s += p[(size_t)r * HIDN];
  hsm[idx] = s * (1.0f / 64.0f);
}

// ---------------- kg partial: hsm @ Wk fp32, split-K ----------------
__global__ __launch_bounds__(256) void kg_partial(const float* __restrict__ hsm,
                                                  const float* __restrict__ Wk,
                                                  float* __restrict__ part) {
  __shared__ float hl[32][256];
  int c = blockIdx.x * 256 + threadIdx.x;
  int k0 = blockIdx.y * 256;
#pragma unroll 4
  for (int i = 0; i < 32; i++) hl[i][threadIdx.x] = hsm[(size_t)i * HIDN + k0 + threadIdx.x];
  __syncthreads();
  float acc[32];
#pragma unroll
  for (int n = 0; n < 32; n++) acc[n] = 0.f;
  for (int k4 = 0; k4 < 64; k4++) {
    float w0 = Wk[(size_t)(k0 + k4 * 4 + 0) * HIDN + c];
    float w1 = Wk[(size_t)(k0 + k4 * 4 + 1) * HIDN + c];
    float w2 = Wk[(size_t)(k0 + k4 * 4 + 2) * HIDN + c];
    float w3 = Wk[(size_t)(k0 + k4 * 4 + 3) * HIDN + c];
#pragma unroll
    for (int n = 0; n < 32; n++) {
      float4 hv = *(const float4*)&hl[n][k4 * 4];
      acc[n] += hv.x * w0 + hv.y * w1 + hv.z * w2 + hv.w * w3;
    }
  }
#pragma unroll
  for (int n = 0; n < 32; n++)
    part[((size_t)blockIdx.y * 32 + n) * HIDN + c] = acc[n];
}

__global__ __launch_bounds__(256) void kg_reduce8(const float* __restrict__ part, float* __restrict__ kg) {
  int idx = blockIdx.x * 256 + threadIdx.x;   // 65536
  float s = 0.f;
#pragma unroll
  for (int kc = 0; kc < 8; kc++) s += part[(size_t)kc * 65536 + idx];
  kg[idx] = s;
}

// ---------------- wg[(h*32+n)][r] = sum_d Wq[r][h*128+d] * kg[n][h*128+d] (fp32) ----------------
__global__ __launch_bounds__(256) void wg_k(const float* __restrict__ Wq, const float* __restrict__ kg,
                                            float* __restrict__ wg) {
  __shared__ float kl[32][128];
  int h = blockIdx.y;
  int r = blockIdx.x * 256 + threadIdx.x;
  for (int i = threadIdx.x; i < 32 * 128; i += 256)
    kl[i >> 7][i & 127] = kg[(size_t)(i >> 7) * HIDN + h * HDIM + (i & 127)];
  __syncthreads();
  float acc[32];
#pragma unroll
  for (int n = 0; n < 32; n++) acc[n] = 0.f;
  const float4* wrow = (const float4*)(Wq + (size_t)r * HIDN + h * HDIM);
  for (int d4 = 0; d4 < 32; d4++) {
    float4 w = wrow[d4];
#pragma unroll
    for (int n = 0; n < 32; n++) {
      float4 kv = *(const float4*)&kl[n][d4 * 4];
      acc[n] += w.x * kv.x + w.y * kv.y + w.z * kv.z + w.w * kv.w;
    }
  }
#pragma unroll
  for (int n = 0; n < 32; n++)
    wg[(size_t)(h * 32 + n) * HIDN + r] = acc[n];
}

// ---------------- gate + top-8 -> 32-bit block mask per (h,s) ----------------
__global__ __launch_bounds__(256) void gate_topk(const float* __restrict__ part,
                                                 unsigned* __restrict__ bsel) {
  int w = threadIdx.x >> 6, L = threadIdx.x & 63;
  int p = blockIdx.x * 4 + w;               // p = h*2048 + s
  int h = p >> 11, s = p & 2047;
  int qb = s >> 6;
  int n = L;
  float g = -1e30f;
  if (n == qb) g = 1e30f;
  else if (n < qb) {
    size_t off = (size_t)s * NGATE + h * 32 + n;
    g = part[off] + part[off + PSTRIDE] + part[off + 2 * PSTRIDE] +
        part[off + 3 * PSTRIDE] + part[off + 4 * PSTRIDE] + part[off + 5 * PSTRIDE];
  }
  int rank = 0;
#pragma unroll
  for (int j = 0; j < 32; j++) {
    float gj = __shfl(g, j, 64);
    if (gj > g || (gj == g && j < n)) rank++;
  }
  bool sel = (n <= qb) && (n < 32) && (rank < 8);
  unsigned long long bm = __ballot(sel);
  if (L == 0) bsel[p] = (unsigned)(bm & 0xffffffffull);
}

// ---------------- V^T per head: vt[h][d][s] ----------------
__global__ __launch_bounds__(256) void vtrans(const bh* __restrict__ qkv, bh* __restrict__ vt) {
  __shared__ float tile[32][33];
  int tx = threadIdx.x, ty = threadIdx.y;
  int s0 = blockIdx.x * 32, d0 = blockIdx.y * 32, h = blockIdx.z;
#pragma unroll
  for (int i = 0; i < 4; i++)
    tile[ty + i * 8][tx] = (float)qkv[(size_t)(s0 + ty + i * 8) * NQKV + 2 * HIDN + h * HDIM + d0 + tx];
  __syncthreads();
#pragma unroll
  for (int i = 0; i < 4; i++)
    vt[((size_t)h * HDIM + d0 + ty + i * 8) * SEQ + s0 + tx] = (bh)tile[tx][ty + i * 8];
}

// ---------------- attn: 1 workgroup (4 waves) per (h, 64-row q-block) ----------------
__global__ __launch_bounds__(256) void attn(const bh* __restrict__ qkv, const bh* __restrict__ vt,
                                            const unsigned* __restrict__ bsel, bh* __restrict__ obuf) {
  __shared__ __align__(16) bh Ks[64 * LDKK];
  __shared__ __align__(16) bh Vs[128 * LDVV];
  __shared__ float PL[4][16 * 68];
  __shared__ unsigned ublk;
  const int t = threadIdx.x;
  const int w = t >> 6, L = t & 63;
  const int quad = L >> 4, lo = L & 15;
  const int qb = blockIdx.x, h = blockIdx.y;
  const int s0 = qb * 64 + w * 16;

  unsigned bs[4];
#pragma unroll
  for (int r = 0; r < 4; r++) bs[r] = bsel[h * SEQ + s0 + quad * 4 + r];
  unsigned uni = bs[0] | bs[1] | bs[2] | bs[3];
  uni |= (unsigned)__shfl_xor((int)uni, 16);
  uni |= (unsigned)__shfl_xor((int)uni, 32);
  if (t == 0) ublk = 0;
  __syncthreads();
  if (L == 0) atomicOr(&ublk, uni);
  __syncthreads();
  const unsigned un = ublk;

  bhx8 aq[4];
  const bh* qrow = qkv + (size_t)(s0 + lo) * NQKV + h * HDIM;
#pragma unroll
  for (int ks = 0; ks < 4; ks++) aq[ks] = *(const bhx8*)(qrow + ks * 32 + quad * 8);

  f32x4 oacc[8];
#pragma unroll
  for (int j = 0; j < 8; j++) oacc[j] = (f32x4){0.f, 0.f, 0.f, 0.f};
  float mi[4] = {-1e30f, -1e30f, -1e30f, -1e30f};
  float li[4] = {0.f, 0.f, 0.f, 0.f};

  const float scale = 0.08838834764831845f;  // 1/sqrt(128)

  for (int n = 0; n <= qb; n++) {
    if (!((un >> n) & 1)) continue;
    {
      const bh* ksrc = qkv + (size_t)(n * BLKSZ) * NQKV + HIDN + h * HDIM;
#pragma unroll
      for (int it = 0; it < 4; it++) {
        int idx = it * 256 + t;            // 1024 chunks: 64 rows x 16
        int row = idx >> 4, cg = idx & 15;
        *(uint4*)&Ks[row * LDKK + cg * 8] = *(const uint4*)(ksrc + (size_t)row * NQKV + cg * 8);
      }
      const bh* vsrc = vt + (size_t)h * HDIM * SEQ + n * BLKSZ;
#pragma unroll
      for (int it = 0; it < 4; it++) {
        int idx = it * 256 + t;            // 1024 chunks: 128 rows x 8
        int row = idx >> 3, cg = idx & 7;
        *(uint4*)&Vs[row * LDVV + cg * 8] = *(const uint4*)(vsrc + (size_t)row * SEQ + cg * 8);
      }
    }
    __syncthreads();

    f32x4 sc[4];
#pragma unroll
    for (int nt = 0; nt < 4; nt++) {
      f32x4 s4 = (f32x4){0.f, 0.f, 0.f, 0.f};
#pragma unroll
      for (int ks = 0; ks < 4; ks++) {
        bhx8 bk = *(const bhx8*)&Ks[(nt * 16 + lo) * LDKK + ks * 32 + quad * 8];
        s4 = __builtin_amdgcn_mfma_f32_16x16x32_bf16(aq[ks], bk, s4, 0, 0, 0);
      }
      sc[nt] = s4;
    }
    const bool self = (n == qb);
#pragma unroll
    for (int nt = 0; nt < 4; nt++)
#pragma unroll
      for (int r = 0; r < 4; r++) {
        float v = sc[nt][r] * scale;
        int kpos = n * BLKSZ + nt * 16 + lo;
        int qpos = s0 + quad * 4 + r;
        bool ok = ((bs[r] >> n) & 1) && (!self || kpos <= qpos);
        sc[nt][r] = ok ? v : -1e30f;
      }
    float rm[4];
#pragma unroll
    for (int r = 0; r < 4; r++)
      rm[r] = fmaxf(fmaxf(sc[0][r], sc[1][r]), fmaxf(sc[2][r], sc[3][r]));
#pragma unroll
    for (int off = 1; off < 16; off <<= 1)
#pragma unroll
      for (int r = 0; r < 4; r++) rm[r] = fmaxf(rm[r], __shfl_xor(rm[r], off));

    float alpha[4], newm[4], rs[4];
#pragma unroll
    for (int r = 0; r < 4; r++) {
      newm[r] = fmaxf(mi[r], rm[r]);
      alpha[r] = __expf(mi[r] - newm[r]);
      rs[r] = 0.f;
    }
#pragma unroll
    for (int nt = 0; nt < 4; nt++)
#pragma unroll
      for (int r = 0; r < 4; r++) {
        float sv = sc[nt][r];
        float pv = (sv > -1e29f) ? __expf(sv - newm[r]) : 0.f;
        PL[w][(quad * 4 + r) * 68 + nt * 16 + lo] = pv;
        rs[r] += pv;
      }
#pragma unroll
    for (int off = 1; off < 16; off <<= 1)
#pragma unroll
      for (int r = 0; r < 4; r++) rs[r] += __shfl_xor(rs[r], off);
#pragma unroll
    for (int r = 0; r < 4; r++) { li[r] = li[r] * alpha[r] + rs[r]; mi[r] = newm[r]; }
#pragma unroll
    for (int j = 0; j < 8; j++)
#pragma unroll
      for (int r = 0; r < 4; r++) oacc[j][r] *= alpha[r];

    __syncthreads();

#pragma unroll
    for (int kk = 0; kk < 2; kk++) {
      const float* prow = &PL[w][lo * 68 + kk * 32 + quad * 8];
      bhx8 pa;
#pragma unroll
      for (int e = 0; e < 8; e++) pa[e] = (bh)prow[e];
#pragma unroll
      for (int j = 0; j < 8; j++) {
        bhx8 vv = *(const bhx8*)&Vs[(j * 16 + lo) * LDVV + kk * 32 + quad * 8];
        oacc[j] = __builtin_amdgcn_mfma_f32_16x16x32_bf16(pa, vv, oacc[j], 0, 0, 0);
      }
    }
    __syncthreads();
  }

#pragma unroll
  for (int j = 0; j < 8; j++)
#pragma unroll
    for (int r = 0; r < 4; r++) {
      int row = s0 + quad * 4 + r;
      int col = h * HDIM + j * 16 + lo;
      obuf[(size_t)row * HIDN + col] = (bh)(oacc[j][r] / li[r]);
    }
}

// ---------------- launch ----------------
extern "C" void kernel_launch(void* const* d_in, const int* in_sizes, int n_in,
                              void* d_out, int out_size, void* d_ws, size_t ws_size,
                              hipStream_t stream) {
  const float* hs = (const float*)d_in[0];
  const float* Wq = (const float*)d_in[1];
  const float* Wk = (const float*)d_in[2];
  const float* Wv = (const float*)d_in[3];
  const float* Wo = (const float*)d_in[4];

  char* ws = (char*)d_ws;
  bh* hs_hi = (bh*)ws;            ws += (size_t)SEQ * HIDN * 2;         // 8 MB
  bh* hs_lo = (bh*)ws;            ws += (size_t)SEQ * HIDN * 2;         // 8 MB
  bh* wqkvT = (bh*)ws;            ws += (size_t)NQKV * HIDN * 2;        // 24 MB
  bh* woT = (bh*)ws;              ws += (size_t)HIDN * HIDN * 2;        // 8 MB
  bh* qkv = (bh*)ws;              ws += (size_t)SEQ * NQKV * 2;         // 24 MB
  bh* vt = (bh*)ws;               ws += (size_t)NHEAD * HDIM * SEQ * 2; // 8 MB
  bh* obuf = (bh*)ws;             ws += (size_t)SEQ * HIDN * 2;         // 8 MB
  float* hsm = (float*)ws;        ws += (size_t)NBLK * HIDN * 4;        // 256 KB
  float* kg_part = (float*)ws;    ws += (size_t)8 * NBLK * HIDN * 4;    // 2 MB
  float* kg = (float*)ws;         ws += (size_t)NBLK * HIDN * 4;        // 256 KB
  float* wg = (float*)ws;         ws += (size_t)NGATE * HIDN * 4;       // 4 MB
  bh* wg_hi = (bh*)ws;            ws += (size_t)NGATE * HIDN * 2;       // 2 MB
  bh* wg_lo = (bh*)ws;            ws += (size_t)NGATE * HIDN * 2;       // 2 MB
  unsigned* bsel = (unsigned*)ws; ws += (size_t)NHEAD * SEQ * 4;        // 128 KB
  // gate partials (6 x 4 MB = 24 MB) alias wqkvT (24 MB): wqkvT is dead after
  // the qkv GEMM, and the stream serializes gemm_bt -> gemm_gate_split.
  float* gpart = (float*)wqkvT;

  // hs split + weight transposes
  split_f32<<<(SEQ * HIDN) / 1024, 256, 0, stream>>>(hs, hs_hi, hs_lo, SEQ * HIDN);
  transpose_cast<<<dim3(64, 64), dim3(32, 8), 0, stream>>>(Wq, wqkvT, HIDN, HIDN);
  transpose_cast<<<dim3(64, 64), dim3(32, 8), 0, stream>>>(Wk, wqkvT + (size_t)HIDN * HIDN, HIDN, HIDN);
  transpose_cast<<<dim3(64, 64), dim3(32, 8), 0, stream>>>(Wv, wqkvT + (size_t)2 * HIDN * HIDN, HIDN, HIDN);
  transpose_cast<<<dim3(64, 64), dim3(32, 8), 0, stream>>>(Wo, woT, HIDN, HIDN);

  // qkv bf16
  gemm_bt<<<dim3(NQKV / 128, SEQ / 128), 256, 0, stream>>>(hs_hi, wqkvT, qkv, SEQ, NQKV, HIDN);

  // fp32 gate path (wqkvT dead from here; gpart aliases it)
  hsmean_k<<<(NBLK * HIDN) / 256, 256, 0, stream>>>(hs, hsm);
  kg_partial<<<dim3(8, 8), 256, 0, stream>>>(hsm, Wk, kg_part);
  kg_reduce8<<<(NBLK * HIDN) / 256, 256, 0, stream>>>(kg_part, kg);
  wg_k<<<dim3(8, NHEAD), 256, 0, stream>>>(Wq, kg, wg);
  split_f32<<<(NGATE * HIDN) / 1024, 256, 0, stream>>>(wg, wg_hi, wg_lo, NGATE * HIDN);
  gemm_gate_split<<<dim3(NGATE / 64, SEQ / 64, 6), 256, 0, stream>>>(hs_hi, hs_lo, wg_hi, wg_lo, gpart);
  gate_topk<<<(NHEAD * SEQ) / 4, 256, 0, stream>>>(gpart, bsel);

  // attention
  vtrans<<<dim3(SEQ / 32, HDIM / 32, NHEAD), dim3(32, 8), 0, stream>>>(qkv, vt);
  attn<<<dim3(NBLK, NHEAD), 256, 0, stream>>>(qkv, vt, bsel, obuf);

  // output projection (64x64 tiles -> 1024 blocks, 4 blocks/CU)
  gemm_bt64<<<dim3(HIDN / 64, SEQ / 64), 256, 0, stream>>>(obuf, woT, (float*)d_out, SEQ, HIDN, HIDN);
}

// Round 5
// 545.528 us; speedup vs baseline: 1.5794x; 1.5794x over previous
//
#include <hip/hip_runtime.h>
#include <hip/hip_bf16.h>
#include <stdint.h>
#include <stddef.h>

// MoBA forward, MI355X.
//  split hs -> bf16 hi/lo; transpose-cast W's -> B^T bf16
//  GEMM1 (bf16 MFMA, LDS-staged coalesced bf16 epilogue): qkv[2048][6144]
//  fp32 gate path: hsmean -> kg (fp32) -> wg = Wq_h @ kg_h (fp32)
//    gate partials = bf16x3 MFMA split 6 ways (3 phases x 2 K-halves)
//  gate_topk: sums 6 partials, rank-based top-8 -> 32-bit block mask
//  attn: block-sparse flash, 1 workgroup (4 waves) per (h, 64-row q-block)
//  GEMM2 (64x64 tile): o @ Wo -> d_out fp32

using bh = __bf16;
typedef __bf16 bhx8 __attribute__((ext_vector_type(8)));
typedef __bf16 bhx4 __attribute__((ext_vector_type(4)));
typedef float  f32x4 __attribute__((ext_vector_type(4)));

#define SEQ   2048
#define HIDN  2048
#define NHEAD 16
#define HDIM  128
#define NBLK  32
#define BLKSZ 64
#define NQKV  6144
#define NGATE 512   // NBLK*NHEAD gate columns
#define LDK   72    // padded LDS row stride for GEMM K-tiles (64+8)
#define LDC   136   // C-tile epilogue stride: 272 B/row = 16B-aligned, 2-way banks (free)
#define LDKK  136   // attn K-tile row stride (128+8)
#define LDVV  72    // attn V-tile row stride (64+8)
#define PSTRIDE ((size_t)SEQ * NGATE)   // gate partial plane stride

// ---------------- split fp32 -> bf16 hi + lo ----------------
__global__ __launch_bounds__(256) void split_f32(const float* __restrict__ in,
                                                 bh* __restrict__ hi, bh* __restrict__ lo, int n) {
  int i = (blockIdx.x * 256 + threadIdx.x) * 4;
  if (i >= n) return;
  float4 v = *(const float4*)(in + i);
  bhx4 h4, l4;
  float vv[4] = {v.x, v.y, v.z, v.w};
#pragma unroll
  for (int e = 0; e < 4; e++) {
    bh h = (bh)vv[e];
    h4[e] = h;
    l4[e] = (bh)(vv[e] - (float)h);
  }
  *(bhx4*)(hi + i) = h4;
  *(bhx4*)(lo + i) = l4;
}

// ---------------- transpose + cast: in[R][C] fp32 -> out[C][R] bf16 ----------------
__global__ __launch_bounds__(256) void transpose_cast(const float* __restrict__ in,
                                                      bh* __restrict__ out, int R, int C) {
  __shared__ float tile[32][33];
  int tx = threadIdx.x, ty = threadIdx.y;
  int c0 = blockIdx.x * 32, r0 = blockIdx.y * 32;
#pragma unroll
  for (int i = 0; i < 4; i++)
    tile[ty + i * 8][tx] = in[(size_t)(r0 + ty + i * 8) * C + c0 + tx];
  __syncthreads();
#pragma unroll
  for (int i = 0; i < 4; i++)
    out[(size_t)(c0 + ty + i * 8) * R + r0 + tx] = (bh)tile[tx][ty + i * 8];
}

// ---------------- bf16 MFMA GEMM 128x128, B^T layout, coalesced bf16 epilogue ----------------
// C[M][N] = A[M][K] * BT[N][K]^T ; bf16 out via LDS restage + uint4 stores.
__global__ __launch_bounds__(256) void gemm_bt(const bh* __restrict__ A, const bh* __restrict__ BT,
                                               bh* __restrict__ Cb, int M, int N, int K) {
  __shared__ __align__(16) bh smem[2 * 128 * LDK];   // 36 KB; reused as 128xLDC C-tile (34 KB)
  bh* As = smem;
  bh* Bs = smem + 128 * LDK;
  const int t = threadIdx.x;
  const int L = t & 63, w = t >> 6;
  const int wm = w & 1, wn = w >> 1;
  const int quad = L >> 4, lo = L & 15;
  const int m0 = blockIdx.y * 128, n0 = blockIdx.x * 128;

  f32x4 acc[4][4];
#pragma unroll
  for (int i = 0; i < 4; i++)
#pragma unroll
    for (int j = 0; j < 4; j++) acc[i][j] = (f32x4){0.f, 0.f, 0.f, 0.f};

  for (int k0 = 0; k0 < K; k0 += 64) {
#pragma unroll
    for (int c = 0; c < 4; c++) {
      int i = c * 256 + t;
      int row = i >> 3, cg = i & 7;
      *(uint4*)&As[row * LDK + cg * 8] = *(const uint4*)(A + (size_t)(m0 + row) * K + k0 + cg * 8);
      *(uint4*)&Bs[row * LDK + cg * 8] = *(const uint4*)(BT + (size_t)(n0 + row) * K + k0 + cg * 8);
    }
    __syncthreads();
#pragma unroll
    for (int ks = 0; ks < 2; ks++) {
      bhx8 af[4], bf_[4];
#pragma unroll
      for (int i = 0; i < 4; i++)
        af[i] = *(const bhx8*)&As[(wm * 64 + i * 16 + lo) * LDK + ks * 32 + quad * 8];
#pragma unroll
      for (int j = 0; j < 4; j++)
        bf_[j] = *(const bhx8*)&Bs[(wn * 64 + j * 16 + lo) * LDK + ks * 32 + quad * 8];
#pragma unroll
      for (int i = 0; i < 4; i++)
#pragma unroll
        for (int j = 0; j < 4; j++)
          acc[i][j] = __builtin_amdgcn_mfma_f32_16x16x32_bf16(af[i], bf_[j], acc[i][j], 0, 0, 0);
    }
    __syncthreads();
  }

  // epilogue: scatter acc -> LDS C-tile, then fully-coalesced 16B global stores
  bh* Cs = smem;
#pragma unroll
  for (int i = 0; i < 4; i++)
#pragma unroll
    for (int j = 0; j < 4; j++)
#pragma unroll
      for (int r = 0; r < 4; r++)
        Cs[(wm * 64 + i * 16 + quad * 4 + r) * LDC + wn * 64 + j * 16 + lo] = (bh)acc[i][j][r];
  __syncthreads();
#pragma unroll
  for (int it = 0; it < 8; it++) {
    int idx = it * 256 + t;                 // 2048 chunks: 128 rows x 16
    int row = idx >> 4, cg = idx & 15;
    *(uint4*)(Cb + (size_t)(m0 + row) * N + n0 + cg * 8) = *(const uint4*)&Cs[row * LDC + cg * 8];
  }
}

// ---------------- bf16 MFMA GEMM 64x64, B^T layout, fp32 out (o-projection) ----------------
__global__ __launch_bounds__(256) void gemm_bt64(const bh* __restrict__ A, const bh* __restrict__ BT,
                                                 float* __restrict__ Cf, int M, int N, int K) {
  __shared__ __align__(16) bh As[64 * LDK];
  __shared__ __align__(16) bh Bs[64 * LDK];
  const int t = threadIdx.x;
  const int L = t & 63, w = t >> 6;
  const int wm = w & 1, wn = w >> 1;
  const int quad = L >> 4, lo = L & 15;
  const int m0 = blockIdx.y * 64, n0 = blockIdx.x * 64;

  f32x4 acc[2][2];
#pragma unroll
  for (int i = 0; i < 2; i++)
#pragma unroll
    for (int j = 0; j < 2; j++) acc[i][j] = (f32x4){0.f, 0.f, 0.f, 0.f};

  for (int k0 = 0; k0 < K; k0 += 64) {
#pragma unroll
    for (int c = 0; c < 2; c++) {
      int i = c * 256 + t;
      int row = i >> 3, cg = i & 7;
      *(uint4*)&As[row * LDK + cg * 8] = *(const uint4*)(A + (size_t)(m0 + row) * K + k0 + cg * 8);
      *(uint4*)&Bs[row * LDK + cg * 8] = *(const uint4*)(BT + (size_t)(n0 + row) * K + k0 + cg * 8);
    }
    __syncthreads();
#pragma unroll
    for (int ks = 0; ks < 2; ks++) {
      bhx8 af[2], bf_[2];
#pragma unroll
      for (int i = 0; i < 2; i++)
        af[i] = *(const bhx8*)&As[(wm * 32 + i * 16 + lo) * LDK + ks * 32 + quad * 8];
#pragma unroll
      for (int j = 0; j < 2; j++)
        bf_[j] = *(const bhx8*)&Bs[(wn * 32 + j * 16 + lo) * LDK + ks * 32 + quad * 8];
#pragma unroll
      for (int i = 0; i < 2; i++)
#pragma unroll
        for (int j = 0; j < 2; j++)
          acc[i][j] = __builtin_amdgcn_mfma_f32_16x16x32_bf16(af[i], bf_[j], acc[i][j], 0, 0, 0);
    }
    __syncthreads();
  }

  // fp32 stores: 16 lanes x 4 B = full 64 B sectors per quad-row (no amplification)
#pragma unroll
  for (int i = 0; i < 2; i++)
#pragma unroll
    for (int j = 0; j < 2; j++)
#pragma unroll
      for (int r = 0; r < 4; r++) {
        int row = m0 + wm * 32 + i * 16 + quad * 4 + r;
        int col = n0 + wn * 32 + j * 16 + lo;
        Cf[(size_t)row * N + col] = acc[i][j][r];
      }
}

// ---------------- gate GEMM, 6-way split for occupancy ----------------
// z = phase*2 + khalf; phase 0: hi@wgh, 1: lo@wgh, 2: hi@wgl; K=1024 each.
__global__ __launch_bounds__(256) void gemm_gate_split(const bh* __restrict__ hs_hi,
                                                       const bh* __restrict__ hs_lo,
                                                       const bh* __restrict__ wg_hi,
                                                       const bh* __restrict__ wg_lo,
                                                       float* __restrict__ part) {
  __shared__ __align__(16) bh As[64 * LDK];
  __shared__ __align__(16) bh Bs[64 * LDK];
  const int t = threadIdx.x;
  const int L = t & 63, w = t >> 6;
  const int wm = w & 1, wn = w >> 1;
  const int quad = L >> 4, lo = L & 15;
  const int m0 = blockIdx.y * 64, n0 = blockIdx.x * 64;
  const int z = blockIdx.z;
  const bh* Ap = ((z >> 1) == 1) ? hs_lo : hs_hi;
  const bh* Bp = ((z >> 1) == 2) ? wg_lo : wg_hi;
  const int kb = (z & 1) * 1024;

  f32x4 acc[2][2];
#pragma unroll
  for (int i = 0; i < 2; i++)
#pragma unroll
    for (int j = 0; j < 2; j++) acc[i][j] = (f32x4){0.f, 0.f, 0.f, 0.f};

  for (int k0 = 0; k0 < 1024; k0 += 64) {
#pragma unroll
    for (int c = 0; c < 2; c++) {
      int i = c * 256 + t;
      int row = i >> 3, cg = i & 7;
      *(uint4*)&As[row * LDK + cg * 8] = *(const uint4*)(Ap + (size_t)(m0 + row) * HIDN + kb + k0 + cg * 8);
      *(uint4*)&Bs[row * LDK + cg * 8] = *(const uint4*)(Bp + (size_t)(n0 + row) * HIDN + kb + k0 + cg * 8);
    }
    __syncthreads();
#pragma unroll
    for (int ks = 0; ks < 2; ks++) {
      bhx8 af[2], bf_[2];
#pragma unroll
      for (int i = 0; i < 2; i++)
        af[i] = *(const bhx8*)&As[(wm * 32 + i * 16 + lo) * LDK + ks * 32 + quad * 8];
#pragma unroll
      for (int j = 0; j < 2; j++)
        bf_[j] = *(const bhx8*)&Bs[(wn * 32 + j * 16 + lo) * LDK + ks * 32 + quad * 8];
#pragma unroll
      for (int i = 0; i < 2; i++)
#pragma unroll
        for (int j = 0; j < 2; j++)
          acc[i][j] = __builtin_amdgcn_mfma_f32_16x16x32_bf16(af[i], bf_[j], acc[i][j], 0, 0, 0);
    }
    __syncthreads();
  }

#pragma unroll
  for (int i = 0; i < 2; i++)
#pragma unroll
    for (int j = 0; j < 2; j++)
#pragma unroll
      for (int r = 0; r < 4; r++) {
        int row = m0 + wm * 32 + i * 16 + quad * 4 + r;
        int col = n0 + wn * 32 + j * 16 + lo;
        part[(size_t)z * PSTRIDE + (size_t)row * NGATE + col] = acc[i][j][r];
      }
}

// ---------------- hsmean: block-mean of hs fp32 -> [NBLK][HIDN] ----------------
__global__ __launch_bounds__(256) void hsmean_k(const float* __restrict__ hs, float* __restrict__ hsm) {
  int idx = blockIdx.x * 256 + threadIdx.x;   // 65536
  int n = idx >> 11, c = idx & 2047;
  const float* p = hs + (size_t)(n * BLKSZ) * HIDN + c;
  float s = 0.f;
#pragma unroll 8
  for (int r = 0; r < BLKSZ; r++) s += p[(size_t)r * HIDN];
  hsm[idx] = s * (1.0f / 64.0f);
}

// ---------------- kg partial: hsm @ Wk fp32, split-K ----------------
__global__ __launch_bounds__(256) void kg_partial(const float* __restrict__ hsm,
                                                  const float* __restrict__ Wk,
                                                  float* __restrict__ part) {
  __shared__ float hl[32][256];
  int c = blockIdx.x * 256 + threadIdx.x;
  int k0 = blockIdx.y * 256;
#pragma unroll 4
  for (int i = 0; i < 32; i++) hl[i][threadIdx.x] = hsm[(size_t)i * HIDN + k0 + threadIdx.x];
  __syncthreads();
  float acc[32];
#pragma unroll
  for (int n = 0; n < 32; n++) acc[n] = 0.f;
  for (int k4 = 0; k4 < 64; k4++) {
    float w0 = Wk[(size_t)(k0 + k4 * 4 + 0) * HIDN + c];
    float w1 = Wk[(size_t)(k0 + k4 * 4 + 1) * HIDN + c];
    float w2 = Wk[(size_t)(k0 + k4 * 4 + 2) * HIDN + c];
    float w3 = Wk[(size_t)(k0 + k4 * 4 + 3) * HIDN + c];
#pragma unroll
    for (int n = 0; n < 32; n++) {
      float4 hv = *(const float4*)&hl[n][k4 * 4];
      acc[n] += hv.x * w0 + hv.y * w1 + hv.z * w2 + hv.w * w3;
    }
  }
#pragma unroll
  for (int n = 0; n < 32; n++)
    part[((size_t)blockIdx.y * 32 + n) * HIDN + c] = acc[n];
}

__global__ __launch_bounds__(256) void kg_reduce8(const float* __restrict__ part, float* __restrict__ kg) {
  int idx = blockIdx.x * 256 + threadIdx.x;   // 65536
  float s = 0.f;
#pragma unroll
  for (int kc = 0; kc < 8; kc++) s += part[(size_t)kc * 65536 + idx];
  kg[idx] = s;
}

// ---------------- wg[(h*32+n)][r] = sum_d Wq[r][h*128+d] * kg[n][h*128+d] (fp32) ----------------
__global__ __launch_bounds__(256) void wg_k(const float* __restrict__ Wq, const float* __restrict__ kg,
                                            float* __restrict__ wg) {
  __shared__ float kl[32][128];
  int h = blockIdx.y;
  int r = blockIdx.x * 256 + threadIdx.x;
  for (int i = threadIdx.x; i < 32 * 128; i += 256)
    kl[i >> 7][i & 127] = kg[(size_t)(i >> 7) * HIDN + h * HDIM + (i & 127)];
  __syncthreads();
  float acc[32];
#pragma unroll
  for (int n = 0; n < 32; n++) acc[n] = 0.f;
  const float4* wrow = (const float4*)(Wq + (size_t)r * HIDN + h * HDIM);
  for (int d4 = 0; d4 < 32; d4++) {
    float4 w = wrow[d4];
#pragma unroll
    for (int n = 0; n < 32; n++) {
      float4 kv = *(const float4*)&kl[n][d4 * 4];
      acc[n] += w.x * kv.x + w.y * kv.y + w.z * kv.z + w.w * kv.w;
    }
  }
#pragma unroll
  for (int n = 0; n < 32; n++)
    wg[(size_t)(h * 32 + n) * HIDN + r] = acc[n];
}

// ---------------- gate + top-8 -> 32-bit block mask per (h,s) ----------------
__global__ __launch_bounds__(256) void gate_topk(const float* __restrict__ part,
                                                 unsigned* __restrict__ bsel) {
  int w = threadIdx.x >> 6, L = threadIdx.x & 63;
  int p = blockIdx.x * 4 + w;               // p = h*2048 + s
  int h = p >> 11, s = p & 2047;
  int qb = s >> 6;
  int n = L;
  float g = -1e30f;
  if (n == qb) g = 1e30f;
  else if (n < qb) {
    size_t off = (size_t)s * NGATE + h * 32 + n;
    g = part[off] + part[off + PSTRIDE] + part[off + 2 * PSTRIDE] +
        part[off + 3 * PSTRIDE] + part[off + 4 * PSTRIDE] + part[off + 5 * PSTRIDE];
  }
  int rank = 0;
#pragma unroll
  for (int j = 0; j < 32; j++) {
    float gj = __shfl(g, j, 64);
    if (gj > g || (gj == g && j < n)) rank++;
  }
  bool sel = (n <= qb) && (n < 32) && (rank < 8);
  unsigned long long bm = __ballot(sel);
  if (L == 0) bsel[p] = (unsigned)(bm & 0xffffffffull);
}

// ---------------- V^T per head: vt[h][d][s] ----------------
__global__ __launch_bounds__(256) void vtrans(const bh* __restrict__ qkv, bh* __restrict__ vt) {
  __shared__ float tile[32][33];
  int tx = threadIdx.x, ty = threadIdx.y;
  int s0 = blockIdx.x * 32, d0 = blockIdx.y * 32, h = blockIdx.z;
#pragma unroll
  for (int i = 0; i < 4; i++)
    tile[ty + i * 8][tx] = (float)qkv[(size_t)(s0 + ty + i * 8) * NQKV + 2 * HIDN + h * HDIM + d0 + tx];
  __syncthreads();
#pragma unroll
  for (int i = 0; i < 4; i++)
    vt[((size_t)h * HDIM + d0 + ty + i * 8) * SEQ + s0 + tx] = (bh)tile[tx][ty + i * 8];
}

// ---------------- attn: 1 workgroup (4 waves) per (h, 64-row q-block) ----------------
__global__ __launch_bounds__(256) void attn(const bh* __restrict__ qkv, const bh* __restrict__ vt,
                                            const unsigned* __restrict__ bsel, bh* __restrict__ obuf) {
  __shared__ __align__(16) bh Ks[64 * LDKK];
  __shared__ __align__(16) bh Vs[128 * LDVV];
  __shared__ float PL[4][16 * 68];
  __shared__ unsigned ublk;
  const int t = threadIdx.x;
  const int w = t >> 6, L = t & 63;
  const int quad = L >> 4, lo = L & 15;
  const int qb = blockIdx.x, h = blockIdx.y;
  const int s0 = qb * 64 + w * 16;

  unsigned bs[4];
#pragma unroll
  for (int r = 0; r < 4; r++) bs[r] = bsel[h * SEQ + s0 + quad * 4 + r];
  unsigned uni = bs[0] | bs[1] | bs[2] | bs[3];
  uni |= (unsigned)__shfl_xor((int)uni, 16);
  uni |= (unsigned)__shfl_xor((int)uni, 32);
  if (t == 0) ublk = 0;
  __syncthreads();
  if (L == 0) atomicOr(&ublk, uni);
  __syncthreads();
  const unsigned un = ublk;

  bhx8 aq[4];
  const bh* qrow = qkv + (size_t)(s0 + lo) * NQKV + h * HDIM;
#pragma unroll
  for (int ks = 0; ks < 4; ks++) aq[ks] = *(const bhx8*)(qrow + ks * 32 + quad * 8);

  f32x4 oacc[8];
#pragma unroll
  for (int j = 0; j < 8; j++) oacc[j] = (f32x4){0.f, 0.f, 0.f, 0.f};
  float mi[4] = {-1e30f, -1e30f, -1e30f, -1e30f};
  float li[4] = {0.f, 0.f, 0.f, 0.f};

  const float scale = 0.08838834764831845f;  // 1/sqrt(128)

  for (int n = 0; n <= qb; n++) {
    if (!((un >> n) & 1)) continue;
    {
      const bh* ksrc = qkv + (size_t)(n * BLKSZ) * NQKV + HIDN + h * HDIM;
#pragma unroll
      for (int it = 0; it < 4; it++) {
        int idx = it * 256 + t;            // 1024 chunks: 64 rows x 16
        int row = idx >> 4, cg = idx & 15;
        *(uint4*)&Ks[row * LDKK + cg * 8] = *(const uint4*)(ksrc + (size_t)row * NQKV + cg * 8);
      }
      const bh* vsrc = vt + (size_t)h * HDIM * SEQ + n * BLKSZ;
#pragma unroll
      for (int it = 0; it < 4; it++) {
        int idx = it * 256 + t;            // 1024 chunks: 128 rows x 8
        int row = idx >> 3, cg = idx & 7;
        *(uint4*)&Vs[row * LDVV + cg * 8] = *(const uint4*)(vsrc + (size_t)row * SEQ + cg * 8);
      }
    }
    __syncthreads();

    f32x4 sc[4];
#pragma unroll
    for (int nt = 0; nt < 4; nt++) {
      f32x4 s4 = (f32x4){0.f, 0.f, 0.f, 0.f};
#pragma unroll
      for (int ks = 0; ks < 4; ks++) {
        bhx8 bk = *(const bhx8*)&Ks[(nt * 16 + lo) * LDKK + ks * 32 + quad * 8];
        s4 = __builtin_amdgcn_mfma_f32_16x16x32_bf16(aq[ks], bk, s4, 0, 0, 0);
      }
      sc[nt] = s4;
    }
    const bool self = (n == qb);
#pragma unroll
    for (int nt = 0; nt < 4; nt++)
#pragma unroll
      for (int r = 0; r < 4; r++) {
        float v = sc[nt][r] * scale;
        int kpos = n * BLKSZ + nt * 16 + lo;
        int qpos = s0 + quad * 4 + r;
        bool ok = ((bs[r] >> n) & 1) && (!self || kpos <= qpos);
        sc[nt][r] = ok ? v : -1e30f;
      }
    float rm[4];
#pragma unroll
    for (int r = 0; r < 4; r++)
      rm[r] = fmaxf(fmaxf(sc[0][r], sc[1][r]), fmaxf(sc[2][r], sc[3][r]));
#pragma unroll
    for (int off = 1; off < 16; off <<= 1)
#pragma unroll
      for (int r = 0; r < 4; r++) rm[r] = fmaxf(rm[r], __shfl_xor(rm[r], off));

    float alpha[4], newm[4], rs[4];
#pragma unroll
    for (int r = 0; r < 4; r++) {
      newm[r] = fmaxf(mi[r], rm[r]);
      alpha[r] = __expf(mi[r] - newm[r]);
      rs[r] = 0.f;
    }
#pragma unroll
    for (int nt = 0; nt < 4; nt++)
#pragma unroll
      for (int r = 0; r < 4; r++) {
        float sv = sc[nt][r];
        float pv = (sv > -1e29f) ? __expf(sv - newm[r]) : 0.f;
        PL[w][(quad * 4 + r) * 68 + nt * 16 + lo] = pv;
        rs[r] += pv;
      }
#pragma unroll
    for (int off = 1; off < 16; off <<= 1)
#pragma unroll
      for (int r = 0; r < 4; r++) rs[r] += __shfl_xor(rs[r], off);
#pragma unroll
    for (int r = 0; r < 4; r++) { li[r] = li[r] * alpha[r] + rs[r]; mi[r] = newm[r]; }
#pragma unroll
    for (int j = 0; j < 8; j++)
#pragma unroll
      for (int r = 0; r < 4; r++) oacc[j][r] *= alpha[r];

    __syncthreads();

#pragma unroll
    for (int kk = 0; kk < 2; kk++) {
      const float* prow = &PL[w][lo * 68 + kk * 32 + quad * 8];
      bhx8 pa;
#pragma unroll
      for (int e = 0; e < 8; e++) pa[e] = (bh)prow[e];
#pragma unroll
      for (int j = 0; j < 8; j++) {
        bhx8 vv = *(const bhx8*)&Vs[(j * 16 + lo) * LDVV + kk * 32 + quad * 8];
        oacc[j] = __builtin_amdgcn_mfma_f32_16x16x32_bf16(pa, vv, oacc[j], 0, 0, 0);
      }
    }
    __syncthreads();
  }

#pragma unroll
  for (int j = 0; j < 8; j++)
#pragma unroll
    for (int r = 0; r < 4; r++) {
      int row = s0 + quad * 4 + r;
      int col = h * HDIM + j * 16 + lo;
      obuf[(size_t)row * HIDN + col] = (bh)(oacc[j][r] / li[r]);
    }
}

// ---------------- launch ----------------
extern "C" void kernel_launch(void* const* d_in, const int* in_sizes, int n_in,
                              void* d_out, int out_size, void* d_ws, size_t ws_size,
                              hipStream_t stream) {
  const float* hs = (const float*)d_in[0];
  const float* Wq = (const float*)d_in[1];
  const float* Wk = (const float*)d_in[2];
  const float* Wv = (const float*)d_in[3];
  const float* Wo = (const float*)d_in[4];

  char* ws = (char*)d_ws;
  bh* hs_hi = (bh*)ws;            ws += (size_t)SEQ * HIDN * 2;         // 8 MB
  bh* hs_lo = (bh*)ws;            ws += (size_t)SEQ * HIDN * 2;         // 8 MB
  bh* wqkvT = (bh*)ws;            ws += (size_t)NQKV * HIDN * 2;        // 24 MB
  bh* woT = (bh*)ws;              ws += (size_t)HIDN * HIDN * 2;        // 8 MB
  bh* qkv = (bh*)ws;              ws += (size_t)SEQ * NQKV * 2;         // 24 MB
  bh* vt = (bh*)ws;               ws += (size_t)NHEAD * HDIM * SEQ * 2; // 8 MB
  bh* obuf = (bh*)ws;             ws += (size_t)SEQ * HIDN * 2;         // 8 MB
  float* hsm = (float*)ws;        ws += (size_t)NBLK * HIDN * 4;        // 256 KB
  float* kg_part = (float*)ws;    ws += (size_t)8 * NBLK * HIDN * 4;    // 2 MB
  float* kg = (float*)ws;         ws += (size_t)NBLK * HIDN * 4;        // 256 KB
  float* wg = (float*)ws;         ws += (size_t)NGATE * HIDN * 4;       // 4 MB
  bh* wg_hi = (bh*)ws;            ws += (size_t)NGATE * HIDN * 2;       // 2 MB
  bh* wg_lo = (bh*)ws;            ws += (size_t)NGATE * HIDN * 2;       // 2 MB
  unsigned* bsel = (unsigned*)ws; ws += (size_t)NHEAD * SEQ * 4;        // 128 KB
  // gate partials (6 x 4 MB = 24 MB) alias wqkvT (24 MB): wqkvT is dead after
  // the qkv GEMM, and the stream serializes gemm_bt -> gemm_gate_split.
  float* gpart = (float*)wqkvT;

  // hs split + weight transposes
  split_f32<<<(SEQ * HIDN) / 1024, 256, 0, stream>>>(hs, hs_hi, hs_lo, SEQ * HIDN);
  transpose_cast<<<dim3(64, 64), dim3(32, 8), 0, stream>>>(Wq, wqkvT, HIDN, HIDN);
  transpose_cast<<<dim3(64, 64), dim3(32, 8), 0, stream>>>(Wk, wqkvT + (size_t)HIDN * HIDN, HIDN, HIDN);
  transpose_cast<<<dim3(64, 64), dim3(32, 8), 0, stream>>>(Wv, wqkvT + (size_t)2 * HIDN * HIDN, HIDN, HIDN);
  transpose_cast<<<dim3(64, 64), dim3(32, 8), 0, stream>>>(Wo, woT, HIDN, HIDN);

  // qkv bf16
  gemm_bt<<<dim3(NQKV / 128, SEQ / 128), 256, 0, stream>>>(hs_hi, wqkvT, qkv, SEQ, NQKV, HIDN);

  // fp32 gate path (wqkvT dead from here; gpart aliases it)
  hsmean_k<<<(NBLK * HIDN) / 256, 256, 0, stream>>>(hs, hsm);
  kg_partial<<<dim3(8, 8), 256, 0, stream>>>(hsm, Wk, kg_part);
  kg_reduce8<<<(NBLK * HIDN) / 256, 256, 0, stream>>>(kg_part, kg);
  wg_k<<<dim3(8, NHEAD), 256, 0, stream>>>(Wq, kg, wg);
  split_f32<<<(NGATE * HIDN) / 1024, 256, 0, stream>>>(wg, wg_hi, wg_lo, NGATE * HIDN);
  gemm_gate_split<<<dim3(NGATE / 64, SEQ / 64, 6), 256, 0, stream>>>(hs_hi, hs_lo, wg_hi, wg_lo, gpart);
  gate_topk<<<(NHEAD * SEQ) / 4, 256, 0, stream>>>(gpart, bsel);

  // attention
  vtrans<<<dim3(SEQ / 32, HDIM / 32, NHEAD), dim3(32, 8), 0, stream>>>(qkv, vt);
  attn<<<dim3(NBLK, NHEAD), 256, 0, stream>>>(qkv, vt, bsel, obuf);

  // output projection (64x64 tiles -> 1024 blocks, 4 blocks/CU)
  gemm_bt64<<<dim3(HIDN / 64, SEQ / 64), 256, 0, stream>>>(obuf, woT, (float*)d_out, SEQ, HIDN, HIDN);
}